// Round 1
// 232.516 us; speedup vs baseline: 1.0768x; 1.0768x over previous
//
#include <hip/hip_runtime.h>
#include <math.h>

#define N_HW 12544
#define TN 128               // n per block tile
#define NCH 98               // 98 * 128 = 12544
#define KB 16                // persistent blocks per batch (each sweeps j = kb, kb+KB, ...)

// ws layout (floats): Sg[64][1024], Qg[64][96], U[64][128]
#define WS_QG 65536
#define WS_U  (WS_QG + 64*96)
#define ZTOT  (WS_U)         // floats to zero (S + Q)

typedef __attribute__((ext_vector_type(8)))  short short8;
typedef __attribute__((ext_vector_type(16))) float f32x16;
typedef __attribute__((ext_vector_type(4)))  float f32x4;

#define MFMA(a, b, c) __builtin_amdgcn_mfma_f32_32x32x16_bf16((a), (b), (c), 0, 0, 0)

// Exact 3-way truncating split: f == H + M + L (24 mantissa bits total).
__device__ __forceinline__ void split3(float f, ushort& h, ushort& m, ushort& l) {
    unsigned u = __builtin_bit_cast(unsigned, f);
    h = (ushort)(u >> 16);
    float fh = __builtin_bit_cast(float, u & 0xffff0000u);
    float rm = f - fh;                                   // exact
    unsigned um = __builtin_bit_cast(unsigned, rm);
    m = (ushort)(um >> 16);
    float fm = __builtin_bit_cast(float, um & 0xffff0000u);
    float rl = rm - fm;                                  // exact, <= 8 sig bits
    l = (ushort)(__builtin_bit_cast(unsigned, rl) >> 16);
}

// XOR-swizzled octet slot in a 32-row x 16-octet bf16 tile.
__device__ __forceinline__ int xq(int c, int o) {
    return c * 16 + ((o & 8) | ((o ^ c) & 7));
}

// ---------------- k0: zero the S/Q accumulators ----------------
__global__ __launch_bounds__(256)
void k0_zero(float* __restrict__ ws)
{
    const int g = blockIdx.x * 256 + threadIdx.x;
    if (g < ZTOT / 4) ((float4*)ws)[g] = make_float4(0.f, 0.f, 0.f, 0.f);
}

// ---------------- k1: persistent MFMA Gram  S += X X^T,  Q += X P ----------------
// Each block owns (b, kb) and sweeps tiles j = kb, kb+KB, ... accumulating in AGPRs.
// Reduce + atomics run ONCE per block (was: once per tile -> 98-way atomic contention).
__global__ __launch_bounds__(256)
void k1_gram(const float* __restrict__ x, const float* __restrict__ p,
             float* __restrict__ Sg, float* __restrict__ Qg)
{
    const int b = blockIdx.y, kb = blockIdx.x;
    const int tid = threadIdx.x;
    const int lane = tid & 63, wave = tid >> 6;

    __shared__ uint4 XS[3 * 512];                         // H/M/L tiles, 24 KB (reused as reduce scratch)
    __shared__ alignas(16) ushort PTH[3 * TN], PTM[3 * TN], PTL[3 * TN];  // P^T tiles [r][n]
    __shared__ float Ssum[1024], T2[1024], T3[1024];      // 12 KB
    float* dmp = (float*)XS;

    const int c = tid >> 3, oc = tid & 7;
    const float* xrow = x + ((size_t)b * 32 + c) * N_HW;
    const float* pbat = p + (size_t)b * N_HW * 3;

    f32x16 D1 = {0,0,0,0,0,0,0,0,0,0,0,0,0,0,0,0};
    f32x16 D2 = {0,0,0,0,0,0,0,0,0,0,0,0,0,0,0,0};
    f32x16 D3 = {0,0,0,0,0,0,0,0,0,0,0,0,0,0,0,0};
    f32x16 DQ = {0,0,0,0,0,0,0,0,0,0,0,0,0,0,0,0};
    const int cl = lane & 31, g = lane >> 5;
    const int rr = (cl < 3) ? cl : 0;

    // ---- prologue: prefetch first tile into regs ----
    float4 pre[4];
    float prep[3];
    int j = kb;
    {
        const float4* xr = (const float4*)(xrow + (size_t)j * TN);
        pre[0] = xr[2 * oc];      pre[1] = xr[2 * oc + 1];
        pre[2] = xr[2 * oc + 16]; pre[3] = xr[2 * oc + 17];
        if (tid < TN) {
            const float* pb = pbat + (size_t)(j * TN + tid) * 3;
            prep[0] = pb[0]; prep[1] = pb[1]; prep[2] = pb[2];
        }
    }

    while (true) {
        // ---- stage X tile from regs: 3-way split -> swizzled bf16 octets ----
        #pragma unroll
        for (int t = 0; t < 2; ++t) {
            const int o = oc + 8 * t;
            float4 f0 = pre[2 * t], f1 = pre[2 * t + 1];
            float fv[8] = {f0.x, f0.y, f0.z, f0.w, f1.x, f1.y, f1.z, f1.w};
            unsigned hw[4], mw[4], lw[4];
            #pragma unroll
            for (int i = 0; i < 4; ++i) {
                ushort h0, m0, l0, h1, m1, l1;
                split3(fv[2 * i],     h0, m0, l0);
                split3(fv[2 * i + 1], h1, m1, l1);
                hw[i] = (unsigned)h0 | ((unsigned)h1 << 16);
                mw[i] = (unsigned)m0 | ((unsigned)m1 << 16);
                lw[i] = (unsigned)l0 | ((unsigned)l1 << 16);
            }
            const int s = xq(c, o);
            XS[s]        = make_uint4(hw[0], hw[1], hw[2], hw[3]);
            XS[512 + s]  = make_uint4(mw[0], mw[1], mw[2], mw[3]);
            XS[1024 + s] = make_uint4(lw[0], lw[1], lw[2], lw[3]);
        }
        if (tid < TN) {
            #pragma unroll
            for (int r = 0; r < 3; ++r) {
                ushort h, m, l;
                split3(prep[r], h, m, l);
                PTH[r * TN + tid] = h; PTM[r * TN + tid] = m; PTL[r * TN + tid] = l;
            }
        }

        // ---- issue next tile's global loads (in flight under barrier + MFMA) ----
        const int jn = j + KB;
        const bool more = (jn < NCH);
        if (more) {
            const float4* xr = (const float4*)(xrow + (size_t)jn * TN);
            pre[0] = xr[2 * oc];      pre[1] = xr[2 * oc + 1];
            pre[2] = xr[2 * oc + 16]; pre[3] = xr[2 * oc + 17];
            if (tid < TN) {
                const float* pb = pbat + (size_t)(jn * TN + tid) * 3;
                prep[0] = pb[0]; prep[1] = pb[1]; prep[2] = pb[2];
            }
        }
        __syncthreads();

        // ---- MFMA K-loop: waves split the 8 K-steps ----
        for (int s = wave; s < 8; s += 4) {
            const int sl = xq(cl, 2 * s + g);
            short8 xh = __builtin_bit_cast(short8, XS[sl]);
            short8 xm = __builtin_bit_cast(short8, XS[512 + sl]);
            short8 xl = __builtin_bit_cast(short8, XS[1024 + sl]);
            const int po = rr * TN + 16 * s + 8 * g;
            short8 ph = *(const short8*)&PTH[po];
            short8 pm = *(const short8*)&PTM[po];
            short8 pl = *(const short8*)&PTL[po];
            D1 = MFMA(xh, xh, D1);          // H H^T
            D1 = MFMA(xm, xm, D1);          // M M^T
            D2 = MFMA(xh, xm, D2);          // H M^T   (+ transpose at reduce)
            D3 = MFMA(xh, xl, D3);          // H L^T   (+ transpose at reduce)
            DQ = MFMA(xh, ph, DQ);
            DQ = MFMA(xh, pm, DQ);
            DQ = MFMA(xm, ph, DQ);
            DQ = MFMA(xh, pl, DQ);
            DQ = MFMA(xl, ph, DQ);
            DQ = MFMA(xm, pm, DQ);
        }

        if (!more) break;
        j = jn;
        __syncthreads();   // MFMA reads done before next staging overwrites XS/PT
    }

    // ---- cross-wave reduce (dump to LDS scratch, stride 20 words: conflict-free b128 writes) ----
    // C/D layout 32x32: col = lane&31, row = (reg&3) + 8*(reg>>2) + 4*(lane>>5)
    #define DUMP_REDUCE(D, dst)                                                            \
        __syncthreads();                                                                   \
        _Pragma("unroll")                                                                  \
        for (int i = 0; i < 4; ++i)                                                        \
            *(float4*)&dmp[tid * 20 + 4 * i] =                                             \
                make_float4((D)[4*i], (D)[4*i+1], (D)[4*i+2], (D)[4*i+3]);                 \
        __syncthreads();                                                                   \
        _Pragma("unroll")                                                                  \
        for (int it = 0; it < 4; ++it) {                                                   \
            const int e = tid + 256 * it;                                                  \
            const int r = e >> 5, co = e & 31;                                             \
            const int ln = co + 32 * ((r >> 2) & 1);                                       \
            const int rg = (r & 3) + 4 * (r >> 3);                                         \
            (dst)[e] = dmp[ln * 20 + rg] + dmp[(64 + ln) * 20 + rg]                        \
                     + dmp[(128 + ln) * 20 + rg] + dmp[(192 + ln) * 20 + rg];              \
        }

    DUMP_REDUCE(D1, Ssum)
    DUMP_REDUCE(D2, T2)
    DUMP_REDUCE(D3, T3)
    __syncthreads();
    {
        float* Sb = Sg + (size_t)b * 1024;
        #pragma unroll
        for (int it = 0; it < 4; ++it) {
            const int e = tid + 256 * it;
            const int r = e >> 5, co = e & 31;
            const int et = (co << 5) | r;
            atomicAdd(&Sb[e], Ssum[e] + T2[e] + T2[et] + T3[e] + T3[et]);
        }
    }
    // ---- Q reduce ----
    __syncthreads();
    #pragma unroll
    for (int i = 0; i < 4; ++i)
        *(float4*)&dmp[tid * 20 + 4 * i] = make_float4(DQ[4*i], DQ[4*i+1], DQ[4*i+2], DQ[4*i+3]);
    __syncthreads();
    if (tid < 96) {
        const int c2 = tid / 3, r2 = tid - 3 * c2;
        const int ln = r2 + 32 * ((c2 >> 2) & 1);
        const int rg = (c2 & 3) + 4 * (c2 >> 3);
        float s = dmp[ln * 20 + rg] + dmp[(64 + ln) * 20 + rg]
                + dmp[(128 + ln) * 20 + rg] + dmp[(192 + ln) * 20 + rg];
        atomicAdd(&Qg[(size_t)b * 96 + tid], s);
    }
}

// ---------------- k2: per-batch V = S*Q0, CholQR2 -> U (32x3, padded to 32x4) ----------------
__global__ __launch_bounds__(128)
void k2_solve(const float* __restrict__ Sg, const float* __restrict__ Qg,
              float* __restrict__ Uo)
{
    const int b = blockIdx.x, tid = threadIdx.x;
    __shared__ float S[1024];
    __shared__ float Qv[96];
    __shared__ float V[96];
    __shared__ float G[6], L[6];

    #pragma unroll
    for (int i = 0; i < 8; ++i) S[tid + 128 * i] = Sg[(size_t)b * 1024 + tid + 128 * i];
    if (tid < 96) Qv[tid] = Qg[(size_t)b * 96 + tid];
    __syncthreads();
    if (tid < 96) {
        const int c = tid / 3, r = tid % 3;
        float s = 0.f;
        #pragma unroll 8
        for (int cc = 0; cc < 32; ++cc) s += S[c * 32 + cc] * Qv[cc * 3 + r];
        V[tid] = s;
    }
    for (int round = 0; round < 2; ++round) {
        __syncthreads();
        if (tid < 6) {
            const int r = (tid > 2) ? 2 : ((tid > 0) ? 1 : 0);
            const int s = tid - (r * (r + 1)) / 2;
            float g = 0.f;
            for (int c = 0; c < 32; ++c) g += V[c * 3 + r] * V[c * 3 + s];
            G[tid] = g;
        }
        __syncthreads();
        if (tid == 0) {
            const float l00 = sqrtf(G[0]);
            const float l10 = G[1] / l00, l20 = G[3] / l00;
            const float l11 = sqrtf(G[2] - l10 * l10);
            const float l21 = (G[4] - l20 * l10) / l11;
            const float l22 = sqrtf(G[5] - l20 * l20 - l21 * l21);
            L[0] = l00; L[1] = l10; L[2] = l11; L[3] = l20; L[4] = l21; L[5] = l22;
        }
        __syncthreads();
        if (tid < 32) {
            const float v0 = V[tid * 3 + 0], v1 = V[tid * 3 + 1], v2 = V[tid * 3 + 2];
            const float u0 = v0 / L[0];
            const float u1 = (v1 - L[1] * u0) / L[2];
            const float u2 = (v2 - L[3] * u0 - L[4] * u1) / L[5];
            V[tid * 3 + 0] = u0; V[tid * 3 + 1] = u1; V[tid * 3 + 2] = u2;
        }
    }
    __syncthreads();
    if (tid < 32) {
        Uo[(size_t)b * 128 + tid * 4 + 0] = V[tid * 3 + 0];
        Uo[(size_t)b * 128 + tid * 4 + 1] = V[tid * 3 + 1];
        Uo[(size_t)b * 128 + tid * 4 + 2] = V[tid * 3 + 2];
        Uo[(size_t)b * 128 + tid * 4 + 3] = 0.f;
    }
}

// ---------------- k3: out = U * (U^T X), pure streaming ----------------
__global__ __launch_bounds__(256)
void k3_out(const float* __restrict__ x, const float* __restrict__ Uw,
            float* __restrict__ out)
{
    const int b = blockIdx.y, tid = threadIdx.x;
    __shared__ float Us[32][4];
    if (tid < 128) ((float*)Us)[tid] = Uw[(size_t)b * 128 + tid];
    __syncthreads();
    const int g = blockIdx.x * 256 + tid;
    if (g >= N_HW / 4) return;

    const float* Xb = x   + (size_t)b * 32 * N_HW + 4 * (size_t)g;
    float*       Ob = out + (size_t)b * 32 * N_HW + 4 * (size_t)g;

    float t0x = 0, t0y = 0, t0z = 0, t0w = 0;
    float t1x = 0, t1y = 0, t1z = 0, t1w = 0;
    float t2x = 0, t2y = 0, t2z = 0, t2w = 0;
    #pragma unroll 16
    for (int c = 0; c < 32; ++c) {
        float4 xv = *(const float4*)(Xb + (size_t)c * N_HW);
        const float u0 = Us[c][0], u1 = Us[c][1], u2 = Us[c][2];
        t0x += u0 * xv.x; t0y += u0 * xv.y; t0z += u0 * xv.z; t0w += u0 * xv.w;
        t1x += u1 * xv.x; t1y += u1 * xv.y; t1z += u1 * xv.z; t1w += u1 * xv.w;
        t2x += u2 * xv.x; t2y += u2 * xv.y; t2z += u2 * xv.z; t2w += u2 * xv.w;
    }
    #pragma unroll 16
    for (int c = 0; c < 32; ++c) {
        const float u0 = Us[c][0], u1 = Us[c][1], u2 = Us[c][2];
        f32x4 o;
        o.x = u0 * t0x + u1 * t1x + u2 * t2x;
        o.y = u0 * t0y + u1 * t1y + u2 * t2y;
        o.z = u0 * t0z + u1 * t1z + u2 * t2z;
        o.w = u0 * t0w + u1 * t1w + u2 * t2w;
        __builtin_nontemporal_store(o, (f32x4*)(Ob + (size_t)c * N_HW));
    }
}

extern "C" void kernel_launch(void* const* d_in, const int* in_sizes, int n_in,
                              void* d_out, int out_size, void* d_ws, size_t ws_size,
                              hipStream_t stream)
{
    const float* x = (const float*)d_in[0];
    const float* p = (const float*)d_in[1];
    float* ws = (float*)d_ws;
    float* Sg = ws;
    float* Qg = ws + WS_QG;
    float* U  = ws + WS_U;
    float* out = (float*)d_out;

    hipLaunchKernelGGL(k0_zero, dim3((ZTOT / 4 + 255) / 256), dim3(256), 0, stream, ws);
    hipLaunchKernelGGL(k1_gram, dim3(KB, 64), dim3(256), 0, stream, x, p, Sg, Qg);
    hipLaunchKernelGGL(k2_solve, dim3(64), dim3(128), 0, stream, Sg, Qg, U);
    hipLaunchKernelGGL(k3_out, dim3((N_HW / 4 + 255) / 256, 64), dim3(256), 0, stream, x, U, out);
}

// Round 2
// 231.756 us; speedup vs baseline: 1.0804x; 1.0033x over previous
//
#include <hip/hip_runtime.h>
#include <math.h>

#define N_HW 12544
#define TN 128               // n per block tile
#define NCH 98               // 98 * 128 = 12544
#define KB 24                // persistent blocks per batch (each sweeps j = kb, kb+KB, ...)

// ws layout (floats): P1[64][KB][1024], P2[64][KB][1024], Qp[64][KB][96], U[64][128]
#define WS_P1 0
#define WS_P2 (64 * KB * 1024)
#define WS_QP (2 * 64 * KB * 1024)
#define WS_U  (WS_QP + 64 * KB * 96)

typedef __attribute__((ext_vector_type(8)))  short short8;
typedef __attribute__((ext_vector_type(16))) float f32x16;
typedef __attribute__((ext_vector_type(4)))  float f32x4;

#define MFMA(a, b, c) __builtin_amdgcn_mfma_f32_32x32x16_bf16((a), (b), (c), 0, 0, 0)

// Exact 3-way truncating split: f == H + M + L (24 mantissa bits total).
__device__ __forceinline__ void split3(float f, ushort& h, ushort& m, ushort& l) {
    unsigned u = __builtin_bit_cast(unsigned, f);
    h = (ushort)(u >> 16);
    float fh = __builtin_bit_cast(float, u & 0xffff0000u);
    float rm = f - fh;                                   // exact
    unsigned um = __builtin_bit_cast(unsigned, rm);
    m = (ushort)(um >> 16);
    float fm = __builtin_bit_cast(float, um & 0xffff0000u);
    float rl = rm - fm;                                  // exact, <= 8 sig bits
    l = (ushort)(__builtin_bit_cast(unsigned, rl) >> 16);
}

// XOR-swizzled octet slot in a 32-row x 16-octet bf16 tile.
__device__ __forceinline__ int xq(int c, int o) {
    return c * 16 + ((o & 8) | ((o ^ c) & 7));
}

// ---------------- k1: persistent MFMA Gram partials ----------------
// Each block owns (b, kb), sweeps j = kb, kb+KB, ... accumulating in regs, then writes
// PRIVATE partial slots (no atomics, no pre-zero):
//   P1 = sum H H^T + M M^T          (symmetric part)
//   P2 = sum H M^T + H L^T          (transpose-added in k2)
//   Qp = X P partial
__global__ __launch_bounds__(256)
void k1_gram(const float* __restrict__ x, const float* __restrict__ p,
             float* __restrict__ P1, float* __restrict__ P2, float* __restrict__ Qp)
{
    const int b = blockIdx.y, kb = blockIdx.x;
    const int tid = threadIdx.x;
    const int lane = tid & 63, wave = tid >> 6;

    __shared__ uint4 XS[3 * 512];                         // H/M/L tiles, 24 KB (reused as reduce scratch)
    __shared__ alignas(16) ushort PTH[3 * TN], PTM[3 * TN], PTL[3 * TN];  // P^T tiles [r][n]
    float* dmp = (float*)XS;

    const int c = tid >> 3, oc = tid & 7;
    const float* xrow = x + ((size_t)b * 32 + c) * N_HW;
    const float* pbat = p + (size_t)b * N_HW * 3;

    f32x16 D1 = {0,0,0,0,0,0,0,0,0,0,0,0,0,0,0,0};
    f32x16 D2 = {0,0,0,0,0,0,0,0,0,0,0,0,0,0,0,0};
    f32x16 DQ = {0,0,0,0,0,0,0,0,0,0,0,0,0,0,0,0};
    const int cl = lane & 31, g = lane >> 5;
    const int rr = (cl < 3) ? cl : 0;

    // ---- prologue: prefetch first tile into regs ----
    float4 pre[4];
    float prep[3];
    int j = kb;
    {
        const float4* xr = (const float4*)(xrow + (size_t)j * TN);
        pre[0] = xr[2 * oc];      pre[1] = xr[2 * oc + 1];
        pre[2] = xr[2 * oc + 16]; pre[3] = xr[2 * oc + 17];
        if (tid < TN) {
            const float* pb = pbat + (size_t)(j * TN + tid) * 3;
            prep[0] = pb[0]; prep[1] = pb[1]; prep[2] = pb[2];
        }
    }

    while (true) {
        // ---- stage X tile from regs: 3-way split -> swizzled bf16 octets ----
        #pragma unroll
        for (int t = 0; t < 2; ++t) {
            const int o = oc + 8 * t;
            float4 f0 = pre[2 * t], f1 = pre[2 * t + 1];
            float fv[8] = {f0.x, f0.y, f0.z, f0.w, f1.x, f1.y, f1.z, f1.w};
            unsigned hw[4], mw[4], lw[4];
            #pragma unroll
            for (int i = 0; i < 4; ++i) {
                ushort h0, m0, l0, h1, m1, l1;
                split3(fv[2 * i],     h0, m0, l0);
                split3(fv[2 * i + 1], h1, m1, l1);
                hw[i] = (unsigned)h0 | ((unsigned)h1 << 16);
                mw[i] = (unsigned)m0 | ((unsigned)m1 << 16);
                lw[i] = (unsigned)l0 | ((unsigned)l1 << 16);
            }
            const int s = xq(c, o);
            XS[s]        = make_uint4(hw[0], hw[1], hw[2], hw[3]);
            XS[512 + s]  = make_uint4(mw[0], mw[1], mw[2], mw[3]);
            XS[1024 + s] = make_uint4(lw[0], lw[1], lw[2], lw[3]);
        }
        if (tid < TN) {
            #pragma unroll
            for (int r = 0; r < 3; ++r) {
                ushort h, m, l;
                split3(prep[r], h, m, l);
                PTH[r * TN + tid] = h; PTM[r * TN + tid] = m; PTL[r * TN + tid] = l;
            }
        }

        // ---- issue next tile's global loads (in flight under barrier + MFMA) ----
        const int jn = j + KB;
        const bool more = (jn < NCH);
        if (more) {
            const float4* xr = (const float4*)(xrow + (size_t)jn * TN);
            pre[0] = xr[2 * oc];      pre[1] = xr[2 * oc + 1];
            pre[2] = xr[2 * oc + 16]; pre[3] = xr[2 * oc + 17];
            if (tid < TN) {
                const float* pb = pbat + (size_t)(jn * TN + tid) * 3;
                prep[0] = pb[0]; prep[1] = pb[1]; prep[2] = pb[2];
            }
        }
        __syncthreads();

        // ---- MFMA K-loop: waves split the 8 K-steps ----
        for (int s = wave; s < 8; s += 4) {
            const int sl = xq(cl, 2 * s + g);
            short8 xh = __builtin_bit_cast(short8, XS[sl]);
            short8 xm = __builtin_bit_cast(short8, XS[512 + sl]);
            short8 xl = __builtin_bit_cast(short8, XS[1024 + sl]);
            const int po = rr * TN + 16 * s + 8 * g;
            short8 ph = *(const short8*)&PTH[po];
            short8 pm = *(const short8*)&PTM[po];
            short8 pl = *(const short8*)&PTL[po];
            D1 = MFMA(xh, xh, D1);          // H H^T
            D1 = MFMA(xm, xm, D1);          // M M^T
            D2 = MFMA(xh, xm, D2);          // H M^T   (+ transpose in k2)
            D2 = MFMA(xh, xl, D2);          // H L^T   (+ transpose in k2)
            DQ = MFMA(xh, ph, DQ);
            DQ = MFMA(xh, pm, DQ);
            DQ = MFMA(xm, ph, DQ);
            DQ = MFMA(xh, pl, DQ);
            DQ = MFMA(xl, ph, DQ);
            DQ = MFMA(xm, pm, DQ);
        }

        if (!more) break;
        j = jn;
        __syncthreads();   // MFMA reads done before next staging overwrites XS/PT
    }

    // ---- cross-wave reduce (dump to LDS scratch, stride 20 words: conflict-free b128 writes) ----
    // C/D layout 32x32: col = lane&31, row = (reg&3) + 8*(reg>>2) + 4*(lane>>5)
    #define DUMP_REDUCE_G(D, gdst)                                                         \
        __syncthreads();                                                                   \
        _Pragma("unroll")                                                                  \
        for (int i = 0; i < 4; ++i)                                                        \
            *(float4*)&dmp[tid * 20 + 4 * i] =                                             \
                make_float4((D)[4*i], (D)[4*i+1], (D)[4*i+2], (D)[4*i+3]);                 \
        __syncthreads();                                                                   \
        _Pragma("unroll")                                                                  \
        for (int it = 0; it < 4; ++it) {                                                   \
            const int e = tid + 256 * it;                                                  \
            const int r = e >> 5, co = e & 31;                                             \
            const int ln = co + 32 * ((r >> 2) & 1);                                       \
            const int rg = (r & 3) + 4 * (r >> 3);                                         \
            (gdst)[e] = dmp[ln * 20 + rg] + dmp[(64 + ln) * 20 + rg]                       \
                      + dmp[(128 + ln) * 20 + rg] + dmp[(192 + ln) * 20 + rg];             \
        }

    float* p1 = P1 + ((size_t)b * KB + kb) * 1024;
    float* p2 = P2 + ((size_t)b * KB + kb) * 1024;
    DUMP_REDUCE_G(D1, p1)
    DUMP_REDUCE_G(D2, p2)

    // ---- Q partial ----
    __syncthreads();
    #pragma unroll
    for (int i = 0; i < 4; ++i)
        *(float4*)&dmp[tid * 20 + 4 * i] = make_float4(DQ[4*i], DQ[4*i+1], DQ[4*i+2], DQ[4*i+3]);
    __syncthreads();
    if (tid < 96) {
        const int c2 = tid / 3, r2 = tid - 3 * c2;
        const int ln = r2 + 32 * ((c2 >> 2) & 1);
        const int rg = (c2 & 3) + 4 * (c2 >> 3);
        float s = dmp[ln * 20 + rg] + dmp[(64 + ln) * 20 + rg]
                + dmp[(128 + ln) * 20 + rg] + dmp[(192 + ln) * 20 + rg];
        Qp[((size_t)b * KB + kb) * 96 + tid] = s;
    }
}

// ---------------- k2: reduce partials -> S, Q; V = S*Q0; CholQR2 -> U (32x3, padded to 32x4) ----
__global__ __launch_bounds__(256)
void k2_solve(const float* __restrict__ P1, const float* __restrict__ P2,
              const float* __restrict__ Qp, float* __restrict__ Uo)
{
    const int b = blockIdx.x, tid = threadIdx.x;
    __shared__ float S[1024], A2[1024];
    __shared__ float Qv[96], V[96], G[6], L[6];

    float a1[4] = {0.f, 0.f, 0.f, 0.f}, a2[4] = {0.f, 0.f, 0.f, 0.f};
    const float* p1 = P1 + (size_t)b * KB * 1024;
    const float* p2 = P2 + (size_t)b * KB * 1024;
    for (int kb = 0; kb < KB; ++kb) {
        #pragma unroll
        for (int i = 0; i < 4; ++i) {
            a1[i] += p1[kb * 1024 + tid + 256 * i];
            a2[i] += p2[kb * 1024 + tid + 256 * i];
        }
    }
    #pragma unroll
    for (int i = 0; i < 4; ++i) A2[tid + 256 * i] = a2[i];
    if (tid < 96) {
        const float* qp = Qp + (size_t)b * KB * 96;
        float q = 0.f;
        for (int kb = 0; kb < KB; ++kb) q += qp[kb * 96 + tid];
        Qv[tid] = q;
    }
    __syncthreads();
    #pragma unroll
    for (int i = 0; i < 4; ++i) {
        const int e = tid + 256 * i;
        const int et = ((e & 31) << 5) | (e >> 5);
        S[e] = a1[i] + a2[i] + A2[et];
    }
    __syncthreads();

    if (tid < 96) {
        const int c = tid / 3, r = tid % 3;
        float s = 0.f;
        #pragma unroll 8
        for (int cc = 0; cc < 32; ++cc) s += S[c * 32 + cc] * Qv[cc * 3 + r];
        V[tid] = s;
    }
    for (int round = 0; round < 2; ++round) {
        __syncthreads();
        if (tid < 6) {
            const int r = (tid > 2) ? 2 : ((tid > 0) ? 1 : 0);
            const int s = tid - (r * (r + 1)) / 2;
            float g = 0.f;
            for (int c = 0; c < 32; ++c) g += V[c * 3 + r] * V[c * 3 + s];
            G[tid] = g;
        }
        __syncthreads();
        if (tid == 0) {
            const float l00 = sqrtf(G[0]);
            const float l10 = G[1] / l00, l20 = G[3] / l00;
            const float l11 = sqrtf(G[2] - l10 * l10);
            const float l21 = (G[4] - l20 * l10) / l11;
            const float l22 = sqrtf(G[5] - l20 * l20 - l21 * l21);
            L[0] = l00; L[1] = l10; L[2] = l11; L[3] = l20; L[4] = l21; L[5] = l22;
        }
        __syncthreads();
        if (tid < 32) {
            const float v0 = V[tid * 3 + 0], v1 = V[tid * 3 + 1], v2 = V[tid * 3 + 2];
            const float u0 = v0 / L[0];
            const float u1 = (v1 - L[1] * u0) / L[2];
            const float u2 = (v2 - L[3] * u0 - L[4] * u1) / L[5];
            V[tid * 3 + 0] = u0; V[tid * 3 + 1] = u1; V[tid * 3 + 2] = u2;
        }
    }
    __syncthreads();
    if (tid < 32) {
        Uo[(size_t)b * 128 + tid * 4 + 0] = V[tid * 3 + 0];
        Uo[(size_t)b * 128 + tid * 4 + 1] = V[tid * 3 + 1];
        Uo[(size_t)b * 128 + tid * 4 + 2] = V[tid * 3 + 2];
        Uo[(size_t)b * 128 + tid * 4 + 3] = 0.f;
    }
}

// ---------------- k3: out = U * (U^T X), pure streaming ----------------
__global__ __launch_bounds__(256)
void k3_out(const float* __restrict__ x, const float* __restrict__ Uw,
            float* __restrict__ out)
{
    const int b = blockIdx.y, tid = threadIdx.x;
    __shared__ float Us[32][4];
    if (tid < 128) ((float*)Us)[tid] = Uw[(size_t)b * 128 + tid];
    __syncthreads();
    const int g = blockIdx.x * 256 + tid;
    if (g >= N_HW / 4) return;

    const float* Xb = x   + (size_t)b * 32 * N_HW + 4 * (size_t)g;
    float*       Ob = out + (size_t)b * 32 * N_HW + 4 * (size_t)g;

    float t0x = 0, t0y = 0, t0z = 0, t0w = 0;
    float t1x = 0, t1y = 0, t1z = 0, t1w = 0;
    float t2x = 0, t2y = 0, t2z = 0, t2w = 0;
    #pragma unroll 16
    for (int c = 0; c < 32; ++c) {
        float4 xv = *(const float4*)(Xb + (size_t)c * N_HW);
        const float u0 = Us[c][0], u1 = Us[c][1], u2 = Us[c][2];
        t0x += u0 * xv.x; t0y += u0 * xv.y; t0z += u0 * xv.z; t0w += u0 * xv.w;
        t1x += u1 * xv.x; t1y += u1 * xv.y; t1z += u1 * xv.z; t1w += u1 * xv.w;
        t2x += u2 * xv.x; t2y += u2 * xv.y; t2z += u2 * xv.z; t2w += u2 * xv.w;
    }
    #pragma unroll 16
    for (int c = 0; c < 32; ++c) {
        const float u0 = Us[c][0], u1 = Us[c][1], u2 = Us[c][2];
        f32x4 o;
        o.x = u0 * t0x + u1 * t1x + u2 * t2x;
        o.y = u0 * t0y + u1 * t1y + u2 * t2y;
        o.z = u0 * t0z + u1 * t1z + u2 * t2z;
        o.w = u0 * t0w + u1 * t1w + u2 * t2w;
        __builtin_nontemporal_store(o, (f32x4*)(Ob + (size_t)c * N_HW));
    }
}

extern "C" void kernel_launch(void* const* d_in, const int* in_sizes, int n_in,
                              void* d_out, int out_size, void* d_ws, size_t ws_size,
                              hipStream_t stream)
{
    const float* x = (const float*)d_in[0];
    const float* p = (const float*)d_in[1];
    float* ws = (float*)d_ws;
    float* P1 = ws + WS_P1;
    float* P2 = ws + WS_P2;
    float* Qp = ws + WS_QP;
    float* U  = ws + WS_U;
    float* out = (float*)d_out;

    hipLaunchKernelGGL(k1_gram, dim3(KB, 64), dim3(256), 0, stream, x, p, P1, P2, Qp);
    hipLaunchKernelGGL(k2_solve, dim3(64), dim3(256), 0, stream, P1, P2, Qp, U);
    hipLaunchKernelGGL(k3_out, dim3((N_HW / 4 + 255) / 256, 64), dim3(256), 0, stream, x, U, out);
}

// Round 3
// 231.562 us; speedup vs baseline: 1.0813x; 1.0008x over previous
//
#include <hip/hip_runtime.h>
#include <math.h>

#define N_HW 12544
#define TN 128               // n per block tile
#define NCH 98               // 98 * 128 = 12544
#define KB 24                // persistent blocks per batch (each sweeps j = kb, kb+KB, ...)

// ws layout (floats): P1[64][KB][1024], P2[64][KB][1024], Qp[64][KB][96], U[64][128]
#define WS_P1 0
#define WS_P2 (64 * KB * 1024)
#define WS_QP (2 * 64 * KB * 1024)
#define WS_U  (WS_QP + 64 * KB * 96)

typedef __attribute__((ext_vector_type(8)))  short short8;
typedef __attribute__((ext_vector_type(16))) float f32x16;
typedef __attribute__((ext_vector_type(4)))  float f32x4;

#define MFMA(a, b, c) __builtin_amdgcn_mfma_f32_32x32x16_bf16((a), (b), (c), 0, 0, 0)

// Barrier WITHOUT vmcnt drain: LDS visibility only. Prefetch global loads stay in flight.
#define LDS_BAR()                                                \
    do {                                                         \
        asm volatile("s_waitcnt lgkmcnt(0)" ::: "memory");       \
        __builtin_amdgcn_s_barrier();                            \
        asm volatile("" ::: "memory");                           \
    } while (0)

// Exact 3-way truncating split: f == H + M + L (24 mantissa bits total).
__device__ __forceinline__ void split3(float f, ushort& h, ushort& m, ushort& l) {
    unsigned u = __builtin_bit_cast(unsigned, f);
    h = (ushort)(u >> 16);
    float fh = __builtin_bit_cast(float, u & 0xffff0000u);
    float rm = f - fh;                                   // exact
    unsigned um = __builtin_bit_cast(unsigned, rm);
    m = (ushort)(um >> 16);
    float fm = __builtin_bit_cast(float, um & 0xffff0000u);
    float rl = rm - fm;                                  // exact, <= 8 sig bits
    l = (ushort)(__builtin_bit_cast(unsigned, rl) >> 16);
}

// XOR-swizzled octet slot in a 32-row x 16-octet bf16 tile.
__device__ __forceinline__ int xq(int c, int o) {
    return c * 16 + ((o & 8) | ((o ^ c) & 7));
}

// ---------------- k1: persistent MFMA Gram partials ----------------
// Each block owns (b, kb), sweeps j = kb, kb+KB, ... with depth-2 register prefetch
// and drain-free barriers; accumulates in regs, writes PRIVATE partial slots:
//   P1 = sum H H^T + M M^T          (symmetric part)
//   P2 = sum H M^T + H L^T          (transpose-added in k2)
//   Qp = X P partial
__global__ __launch_bounds__(256)
void k1_gram(const float* __restrict__ x, const float* __restrict__ p,
             float* __restrict__ P1, float* __restrict__ P2, float* __restrict__ Qp)
{
    const int b = blockIdx.y, kb = blockIdx.x;
    const int tid = threadIdx.x;
    const int lane = tid & 63, wave = tid >> 6;

    __shared__ uint4 XS[3 * 512];                         // H/M/L tiles, 24 KB (reused as reduce scratch)
    __shared__ alignas(16) ushort PTH[3 * TN], PTM[3 * TN], PTL[3 * TN];  // P^T tiles [r][n]
    float* dmp = (float*)XS;

    const int c = tid >> 3, oc = tid & 7;
    const float* xrow = x + ((size_t)b * 32 + c) * N_HW;
    const float* pbat = p + (size_t)b * N_HW * 3;

    f32x16 D1 = {0,0,0,0,0,0,0,0,0,0,0,0,0,0,0,0};
    f32x16 D2 = {0,0,0,0,0,0,0,0,0,0,0,0,0,0,0,0};
    f32x16 DQ = {0,0,0,0,0,0,0,0,0,0,0,0,0,0,0,0};
    const int cl = lane & 31, g = lane >> 5;
    const int rr = (cl < 3) ? cl : 0;

#define LOADX(PX, jj)                                                          \
    do {                                                                       \
        const float4* xr = (const float4*)(xrow + (size_t)(jj) * TN);          \
        PX[0] = xr[2 * oc];      PX[1] = xr[2 * oc + 1];                       \
        PX[2] = xr[2 * oc + 16]; PX[3] = xr[2 * oc + 17];                      \
    } while (0)

#define LOADP(PP, jj)                                                          \
    do { if (tid < TN) {                                                       \
        const float* pb = pbat + (size_t)((jj) * TN + tid) * 3;                \
        PP[0] = pb[0]; PP[1] = pb[1]; PP[2] = pb[2];                           \
    } } while (0)

#define STAGE(PX, PP)                                                          \
    do {                                                                       \
        _Pragma("unroll")                                                      \
        for (int t = 0; t < 2; ++t) {                                          \
            const int o = oc + 8 * t;                                          \
            float4 f0 = PX[2 * t], f1 = PX[2 * t + 1];                         \
            float fv[8] = {f0.x, f0.y, f0.z, f0.w, f1.x, f1.y, f1.z, f1.w};    \
            unsigned hw[4], mw[4], lw[4];                                      \
            _Pragma("unroll")                                                  \
            for (int i = 0; i < 4; ++i) {                                      \
                ushort h0, m0, l0, h1, m1, l1;                                 \
                split3(fv[2 * i],     h0, m0, l0);                             \
                split3(fv[2 * i + 1], h1, m1, l1);                             \
                hw[i] = (unsigned)h0 | ((unsigned)h1 << 16);                   \
                mw[i] = (unsigned)m0 | ((unsigned)m1 << 16);                   \
                lw[i] = (unsigned)l0 | ((unsigned)l1 << 16);                   \
            }                                                                  \
            const int s = xq(c, o);                                            \
            XS[s]        = make_uint4(hw[0], hw[1], hw[2], hw[3]);             \
            XS[512 + s]  = make_uint4(mw[0], mw[1], mw[2], mw[3]);             \
            XS[1024 + s] = make_uint4(lw[0], lw[1], lw[2], lw[3]);             \
        }                                                                      \
        if (tid < TN) {                                                        \
            _Pragma("unroll")                                                  \
            for (int r = 0; r < 3; ++r) {                                      \
                ushort h, m, l;                                                \
                split3(PP[r], h, m, l);                                        \
                PTH[r * TN + tid] = h; PTM[r * TN + tid] = m;                  \
                PTL[r * TN + tid] = l;                                         \
            }                                                                  \
        }                                                                      \
    } while (0)

#define MFMA_PHASE()                                                           \
    do {                                                                       \
        __builtin_amdgcn_s_setprio(1);                                         \
        for (int s = wave; s < 8; s += 4) {                                    \
            const int sl = xq(cl, 2 * s + g);                                  \
            short8 xh = __builtin_bit_cast(short8, XS[sl]);                    \
            short8 xm = __builtin_bit_cast(short8, XS[512 + sl]);              \
            short8 xl = __builtin_bit_cast(short8, XS[1024 + sl]);             \
            const int po = rr * TN + 16 * s + 8 * g;                           \
            short8 ph = *(const short8*)&PTH[po];                              \
            short8 pm = *(const short8*)&PTM[po];                              \
            short8 pl = *(const short8*)&PTL[po];                              \
            D1 = MFMA(xh, xh, D1);                                             \
            D1 = MFMA(xm, xm, D1);                                             \
            D2 = MFMA(xh, xm, D2);                                             \
            D2 = MFMA(xh, xl, D2);                                             \
            DQ = MFMA(xh, ph, DQ);                                             \
            DQ = MFMA(xh, pm, DQ);                                             \
            DQ = MFMA(xm, ph, DQ);                                             \
            DQ = MFMA(xh, pl, DQ);                                             \
            DQ = MFMA(xl, ph, DQ);                                             \
            DQ = MFMA(xm, pm, DQ);                                             \
        }                                                                      \
        __builtin_amdgcn_s_setprio(0);                                         \
    } while (0)

    // ---- depth-2 prefetch pipeline over tiles j = kb, kb+KB, ... ----
    float4 XA[4], XB[4];
    float  PA[3], PB[3];
    int j = kb, jB = kb + KB;
    LOADX(XA, j); LOADP(PA, j);
    bool hasB = (jB < NCH);
    if (hasB) { LOADX(XB, jB); LOADP(PB, jB); }

    while (true) {
        // ---- even tile (set A) ----
        STAGE(XA, PA);
        const int jn = j + 2 * KB;
        const bool preA = (jn < NCH);
        if (preA) { LOADX(XA, jn); LOADP(PA, jn); }
        LDS_BAR();
        MFMA_PHASE();
        if (!hasB) break;
        LDS_BAR();

        // ---- odd tile (set B) ----
        STAGE(XB, PB);
        const int jn2 = jB + 2 * KB;
        const bool preB = (jn2 < NCH);
        if (preB) { LOADX(XB, jn2); LOADP(PB, jn2); }
        LDS_BAR();
        MFMA_PHASE();
        if (!preA) break;
        LDS_BAR();

        j = jn; jB = jn2; hasB = preB;
    }

    // ---- cross-wave reduce (dump to LDS scratch, stride 20 words: conflict-free b128 writes) ----
    // C/D layout 32x32: col = lane&31, row = (reg&3) + 8*(reg>>2) + 4*(lane>>5)
    #define DUMP_REDUCE_G(D, gdst)                                                         \
        __syncthreads();                                                                   \
        _Pragma("unroll")                                                                  \
        for (int i = 0; i < 4; ++i)                                                        \
            *(float4*)&dmp[tid * 20 + 4 * i] =                                             \
                make_float4((D)[4*i], (D)[4*i+1], (D)[4*i+2], (D)[4*i+3]);                 \
        __syncthreads();                                                                   \
        _Pragma("unroll")                                                                  \
        for (int it = 0; it < 4; ++it) {                                                   \
            const int e = tid + 256 * it;                                                  \
            const int r = e >> 5, co = e & 31;                                             \
            const int ln = co + 32 * ((r >> 2) & 1);                                       \
            const int rg = (r & 3) + 4 * (r >> 3);                                         \
            (gdst)[e] = dmp[ln * 20 + rg] + dmp[(64 + ln) * 20 + rg]                       \
                      + dmp[(128 + ln) * 20 + rg] + dmp[(192 + ln) * 20 + rg];             \
        }

    float* p1 = P1 + ((size_t)b * KB + kb) * 1024;
    float* p2 = P2 + ((size_t)b * KB + kb) * 1024;
    DUMP_REDUCE_G(D1, p1)
    DUMP_REDUCE_G(D2, p2)

    // ---- Q partial ----
    __syncthreads();
    #pragma unroll
    for (int i = 0; i < 4; ++i)
        *(float4*)&dmp[tid * 20 + 4 * i] = make_float4(DQ[4*i], DQ[4*i+1], DQ[4*i+2], DQ[4*i+3]);
    __syncthreads();
    if (tid < 96) {
        const int c2 = tid / 3, r2 = tid - 3 * c2;
        const int ln = r2 + 32 * ((c2 >> 2) & 1);
        const int rg = (c2 & 3) + 4 * (c2 >> 3);
        float s = dmp[ln * 20 + rg] + dmp[(64 + ln) * 20 + rg]
                + dmp[(128 + ln) * 20 + rg] + dmp[(192 + ln) * 20 + rg];
        Qp[((size_t)b * KB + kb) * 96 + tid] = s;
    }
}

// ---------------- k2: reduce partials -> S, Q; V = S*Q0; CholQR2 -> U (32x3, padded to 32x4) ----
__global__ __launch_bounds__(256)
void k2_solve(const float* __restrict__ P1, const float* __restrict__ P2,
              const float* __restrict__ Qp, float* __restrict__ Uo)
{
    const int b = blockIdx.x, tid = threadIdx.x;
    __shared__ float S[1024], A2[1024];
    __shared__ float Qv[96], V[96], G[6], L[6];

    // thread owns elements e = 4*tid .. 4*tid+3 (float4 loads, unrolled for MLP)
    f32x4 a1 = {0.f, 0.f, 0.f, 0.f}, a2 = {0.f, 0.f, 0.f, 0.f};
    const float4* p1 = (const float4*)(P1 + (size_t)b * KB * 1024);
    const float4* p2 = (const float4*)(P2 + (size_t)b * KB * 1024);
    #pragma unroll 4
    for (int kb = 0; kb < KB; ++kb) {
        float4 v1 = p1[kb * 256 + tid];
        float4 v2 = p2[kb * 256 + tid];
        a1.x += v1.x; a1.y += v1.y; a1.z += v1.z; a1.w += v1.w;
        a2.x += v2.x; a2.y += v2.y; a2.z += v2.z; a2.w += v2.w;
    }
    A2[4 * tid + 0] = a2.x; A2[4 * tid + 1] = a2.y;
    A2[4 * tid + 2] = a2.z; A2[4 * tid + 3] = a2.w;
    if (tid < 96) {
        const float* qp = Qp + (size_t)b * KB * 96;
        float q = 0.f;
        #pragma unroll 4
        for (int kb = 0; kb < KB; ++kb) q += qp[kb * 96 + tid];
        Qv[tid] = q;
    }
    __syncthreads();
    #pragma unroll
    for (int i = 0; i < 4; ++i) {
        const int e = 4 * tid + i;
        const int et = ((e & 31) << 5) | (e >> 5);
        S[e] = ((i == 0) ? a1.x : (i == 1) ? a1.y : (i == 2) ? a1.z : a1.w)
             + ((i == 0) ? a2.x : (i == 1) ? a2.y : (i == 2) ? a2.z : a2.w)
             + A2[et];
    }
    __syncthreads();

    if (tid < 96) {
        const int c = tid / 3, r = tid % 3;
        float s = 0.f;
        #pragma unroll 8
        for (int cc = 0; cc < 32; ++cc) s += S[c * 32 + cc] * Qv[cc * 3 + r];
        V[tid] = s;
    }
    for (int round = 0; round < 2; ++round) {
        __syncthreads();
        if (tid < 6) {
            const int r = (tid > 2) ? 2 : ((tid > 0) ? 1 : 0);
            const int s = tid - (r * (r + 1)) / 2;
            float g = 0.f;
            for (int c = 0; c < 32; ++c) g += V[c * 3 + r] * V[c * 3 + s];
            G[tid] = g;
        }
        __syncthreads();
        if (tid == 0) {
            const float l00 = sqrtf(G[0]);
            const float l10 = G[1] / l00, l20 = G[3] / l00;
            const float l11 = sqrtf(G[2] - l10 * l10);
            const float l21 = (G[4] - l20 * l10) / l11;
            const float l22 = sqrtf(G[5] - l20 * l20 - l21 * l21);
            L[0] = l00; L[1] = l10; L[2] = l11; L[3] = l20; L[4] = l21; L[5] = l22;
        }
        __syncthreads();
        if (tid < 32) {
            const float v0 = V[tid * 3 + 0], v1 = V[tid * 3 + 1], v2 = V[tid * 3 + 2];
            const float u0 = v0 / L[0];
            const float u1 = (v1 - L[1] * u0) / L[2];
            const float u2 = (v2 - L[3] * u0 - L[4] * u1) / L[5];
            V[tid * 3 + 0] = u0; V[tid * 3 + 1] = u1; V[tid * 3 + 2] = u2;
        }
    }
    __syncthreads();
    if (tid < 32) {
        Uo[(size_t)b * 128 + tid * 4 + 0] = V[tid * 3 + 0];
        Uo[(size_t)b * 128 + tid * 4 + 1] = V[tid * 3 + 1];
        Uo[(size_t)b * 128 + tid * 4 + 2] = V[tid * 3 + 2];
        Uo[(size_t)b * 128 + tid * 4 + 3] = 0.f;
    }
}

// ---------------- k3: out = U * (U^T X), pure streaming ----------------
__global__ __launch_bounds__(256)
void k3_out(const float* __restrict__ x, const float* __restrict__ Uw,
            float* __restrict__ out)
{
    const int b = blockIdx.y, tid = threadIdx.x;
    __shared__ float Us[32][4];
    if (tid < 128) ((float*)Us)[tid] = Uw[(size_t)b * 128 + tid];
    __syncthreads();
    const int g = blockIdx.x * 256 + tid;
    if (g >= N_HW / 4) return;

    const float* Xb = x   + (size_t)b * 32 * N_HW + 4 * (size_t)g;
    float*       Ob = out + (size_t)b * 32 * N_HW + 4 * (size_t)g;

    float t0x = 0, t0y = 0, t0z = 0, t0w = 0;
    float t1x = 0, t1y = 0, t1z = 0, t1w = 0;
    float t2x = 0, t2y = 0, t2z = 0, t2w = 0;
    #pragma unroll 16
    for (int c = 0; c < 32; ++c) {
        float4 xv = *(const float4*)(Xb + (size_t)c * N_HW);
        const float u0 = Us[c][0], u1 = Us[c][1], u2 = Us[c][2];
        t0x += u0 * xv.x; t0y += u0 * xv.y; t0z += u0 * xv.z; t0w += u0 * xv.w;
        t1x += u1 * xv.x; t1y += u1 * xv.y; t1z += u1 * xv.z; t1w += u1 * xv.w;
        t2x += u2 * xv.x; t2y += u2 * xv.y; t2z += u2 * xv.z; t2w += u2 * xv.w;
    }
    #pragma unroll 16
    for (int c = 0; c < 32; ++c) {
        const float u0 = Us[c][0], u1 = Us[c][1], u2 = Us[c][2];
        f32x4 o;
        o.x = u0 * t0x + u1 * t1x + u2 * t2x;
        o.y = u0 * t0y + u1 * t1y + u2 * t2y;
        o.z = u0 * t0z + u1 * t1z + u2 * t2z;
        o.w = u0 * t0w + u1 * t1w + u2 * t2w;
        __builtin_nontemporal_store(o, (f32x4*)(Ob + (size_t)c * N_HW));
    }
}

extern "C" void kernel_launch(void* const* d_in, const int* in_sizes, int n_in,
                              void* d_out, int out_size, void* d_ws, size_t ws_size,
                              hipStream_t stream)
{
    const float* x = (const float*)d_in[0];
    const float* p = (const float*)d_in[1];
    float* ws = (float*)d_ws;
    float* P1 = ws + WS_P1;
    float* P2 = ws + WS_P2;
    float* Qp = ws + WS_QP;
    float* U  = ws + WS_U;
    float* out = (float*)d_out;

    hipLaunchKernelGGL(k1_gram, dim3(KB, 64), dim3(256), 0, stream, x, p, P1, P2, Qp);
    hipLaunchKernelGGL(k2_solve, dim3(64), dim3(256), 0, stream, P1, P2, Qp, U);
    hipLaunchKernelGGL(k3_out, dim3((N_HW / 4 + 255) / 256, 64), dim3(256), 0, stream, x, U, out);
}

// Round 5
// 226.863 us; speedup vs baseline: 1.1037x; 1.0207x over previous
//
#include <hip/hip_runtime.h>
#include <math.h>

#define N_HW 12544
#define TN 128               // n per block tile
#define NCH 98               // 98 * 128 = 12544
#define KB 16                // persistent blocks per batch (each sweeps j = kb, kb+KB, ...)

// ws layout (floats): P1[64][KB][1024], P2[64][KB][1024], Qp[64][KB][96], U[64][128]
#define WS_P1 0
#define WS_P2 (64 * KB * 1024)
#define WS_QP (2 * 64 * KB * 1024)
#define WS_U  (WS_QP + 64 * KB * 96)

typedef __attribute__((ext_vector_type(8)))  short short8;
typedef __attribute__((ext_vector_type(16))) float f32x16;
typedef __attribute__((ext_vector_type(4)))  float f32x4;

#define MFMA(a, b, c) __builtin_amdgcn_mfma_f32_32x32x16_bf16((a), (b), (c), 0, 0, 0)

// Barrier WITHOUT vmcnt drain: LDS visibility only. Prefetch global loads stay in flight.
#define LDS_BAR()                                                \
    do {                                                         \
        asm volatile("s_waitcnt lgkmcnt(0)" ::: "memory");       \
        __builtin_amdgcn_s_barrier();                            \
        asm volatile("" ::: "memory");                           \
    } while (0)

// 2-way split, 16 mantissa bits captured: f ~= H + M, M rounded-to-nearest (unbiased,
// |err| <= 2^-17 rel). Output error budget is dominated by the structural ~2^-7
// CholQR-vs-QR difference, so 16-bit X is ample (was exact 24-bit 3-plane).
__device__ __forceinline__ void split2(float f, ushort& h, ushort& m) {
    unsigned u = __builtin_bit_cast(unsigned, f);
    h = (ushort)(u >> 16);
    float fh = __builtin_bit_cast(float, u & 0xffff0000u);
    float rm = f - fh;                                   // exact remainder
    unsigned um = __builtin_bit_cast(unsigned, rm);
    um += 0x7fffu + ((um >> 16) & 1u);                   // RNE to bf16
    m = (ushort)(um >> 16);
}

// XOR-swizzled octet slot in a 32-row x 16-octet bf16 tile.
__device__ __forceinline__ int xq(int c, int o) {
    return c * 16 + ((o & 8) | ((o ^ c) & 7));
}

// ---------------- k1: persistent MFMA Gram partials (2-plane) ----------------
// Each block owns (b, kb), sweeps j = kb, kb+KB, ... with depth-2 register prefetch
// and drain-free barriers; accumulates in regs, writes PRIVATE partial slots:
//   P1 = sum H H^T + M M^T          (symmetric part)
//   P2 = sum H M^T                  (transpose-added in k2)
//   Qp = (H+M)(h+m) partial         (X*P)
__global__ __launch_bounds__(256)
void k1_gram(const float* __restrict__ x, const float* __restrict__ p,
             float* __restrict__ P1, float* __restrict__ P2, float* __restrict__ Qp)
{
    const int b = blockIdx.y, kb = blockIdx.x;
    const int tid = threadIdx.x;
    const int lane = tid & 63, wave = tid >> 6;

    // SMEM union: XS staging (2 planes x 512 uint4 = 16 KB) / reduce scratch (20 KB)
    __shared__ alignas(16) float SMEM[5120];
    uint4* XS  = (uint4*)SMEM;
    float* dmp = SMEM;
    __shared__ alignas(16) ushort PTH[3 * TN], PTM[3 * TN];   // P^T tiles [r][n]

    const int c = tid >> 3, oc = tid & 7;
    const float* xrow = x + ((size_t)b * 32 + c) * N_HW;
    const float* pbat = p + (size_t)b * N_HW * 3;

    f32x16 D1 = {0,0,0,0,0,0,0,0,0,0,0,0,0,0,0,0};
    f32x16 D2 = {0,0,0,0,0,0,0,0,0,0,0,0,0,0,0,0};
    f32x16 DQ = {0,0,0,0,0,0,0,0,0,0,0,0,0,0,0,0};
    const int cl = lane & 31, g = lane >> 5;
    const int rr = (cl < 3) ? cl : 0;

#define LOADX(PX, jj)                                                          \
    do {                                                                       \
        const float4* xr = (const float4*)(xrow + (size_t)(jj) * TN);          \
        PX[0] = xr[2 * oc];      PX[1] = xr[2 * oc + 1];                       \
        PX[2] = xr[2 * oc + 16]; PX[3] = xr[2 * oc + 17];                      \
    } while (0)

#define LOADP(PP, jj)                                                          \
    do { if (tid < TN) {                                                       \
        const float* pb = pbat + (size_t)((jj) * TN + tid) * 3;                \
        PP[0] = pb[0]; PP[1] = pb[1]; PP[2] = pb[2];                           \
    } } while (0)

#define STAGE(PX, PP)                                                          \
    do {                                                                       \
        _Pragma("unroll")                                                      \
        for (int t = 0; t < 2; ++t) {                                          \
            const int o = oc + 8 * t;                                          \
            float4 f0 = PX[2 * t], f1 = PX[2 * t + 1];                         \
            float fv[8] = {f0.x, f0.y, f0.z, f0.w, f1.x, f1.y, f1.z, f1.w};    \
            unsigned hw[4], mw[4];                                             \
            _Pragma("unroll")                                                  \
            for (int i = 0; i < 4; ++i) {                                      \
                ushort h0, m0, h1, m1;                                         \
                split2(fv[2 * i],     h0, m0);                                 \
                split2(fv[2 * i + 1], h1, m1);                                 \
                hw[i] = (unsigned)h0 | ((unsigned)h1 << 16);                   \
                mw[i] = (unsigned)m0 | ((unsigned)m1 << 16);                   \
            }                                                                  \
            const int s = xq(c, o);                                            \
            XS[s]       = make_uint4(hw[0], hw[1], hw[2], hw[3]);              \
            XS[512 + s] = make_uint4(mw[0], mw[1], mw[2], mw[3]);              \
        }                                                                      \
        if (tid < TN) {                                                        \
            _Pragma("unroll")                                                  \
            for (int r = 0; r < 3; ++r) {                                      \
                ushort h, m;                                                   \
                split2(PP[r], h, m);                                           \
                PTH[r * TN + tid] = h; PTM[r * TN + tid] = m;                  \
            }                                                                  \
        }                                                                      \
    } while (0)

#define MFMA_PHASE()                                                           \
    do {                                                                       \
        __builtin_amdgcn_s_setprio(1);                                         \
        for (int s = wave; s < 8; s += 4) {                                    \
            const int sl = xq(cl, 2 * s + g);                                  \
            short8 xh = __builtin_bit_cast(short8, XS[sl]);                    \
            short8 xm = __builtin_bit_cast(short8, XS[512 + sl]);              \
            const int po = rr * TN + 16 * s + 8 * g;                           \
            short8 ph = *(const short8*)&PTH[po];                              \
            short8 pm = *(const short8*)&PTM[po];                              \
            D1 = MFMA(xh, xh, D1);                                             \
            D1 = MFMA(xm, xm, D1);                                             \
            D2 = MFMA(xh, xm, D2);                                             \
            DQ = MFMA(xh, ph, DQ);                                             \
            DQ = MFMA(xm, ph, DQ);                                             \
            DQ = MFMA(xh, pm, DQ);                                             \
            DQ = MFMA(xm, pm, DQ);                                             \
        }                                                                      \
        __builtin_amdgcn_s_setprio(0);                                         \
    } while (0)

    // ---- depth-2 prefetch pipeline over tiles j = kb, kb+KB, ... ----
    float4 XA[4], XB[4];
    float  PA[3], PB[3];
    int j = kb, jB = kb + KB;
    LOADX(XA, j); LOADP(PA, j);
    bool hasB = (jB < NCH);
    if (hasB) { LOADX(XB, jB); LOADP(PB, jB); }

    while (true) {
        // ---- even tile (set A) ----
        STAGE(XA, PA);
        const int jn = j + 2 * KB;
        const bool preA = (jn < NCH);
        if (preA) { LOADX(XA, jn); LOADP(PA, jn); }
        LDS_BAR();
        MFMA_PHASE();
        if (!hasB) break;
        LDS_BAR();

        // ---- odd tile (set B) ----
        STAGE(XB, PB);
        const int jn2 = jB + 2 * KB;
        const bool preB = (jn2 < NCH);
        if (preB) { LOADX(XB, jn2); LOADP(PB, jn2); }
        LDS_BAR();
        MFMA_PHASE();
        if (!preA) break;
        LDS_BAR();

        j = jn; jB = jn2; hasB = preB;
    }

    // ---- cross-wave reduce (dump to LDS scratch, stride 20 words: conflict-free b128 writes) ----
    // C/D layout 32x32: col = lane&31, row = (reg&3) + 8*(reg>>2) + 4*(lane>>5)
    #define DUMP_REDUCE_G(D, gdst)                                                         \
        __syncthreads();                                                                   \
        _Pragma("unroll")                                                                  \
        for (int i = 0; i < 4; ++i)                                                        \
            *(float4*)&dmp[tid * 20 + 4 * i] =                                             \
                make_float4((D)[4*i], (D)[4*i+1], (D)[4*i+2], (D)[4*i+3]);                 \
        __syncthreads();                                                                   \
        _Pragma("unroll")                                                                  \
        for (int it = 0; it < 4; ++it) {                                                   \
            const int e = tid + 256 * it;                                                  \
            const int r = e >> 5, co = e & 31;                                             \
            const int ln = co + 32 * ((r >> 2) & 1);                                       \
            const int rg = (r & 3) + 4 * (r >> 3);                                         \
            (gdst)[e] = dmp[ln * 20 + rg] + dmp[(64 + ln) * 20 + rg]                       \
                      + dmp[(128 + ln) * 20 + rg] + dmp[(192 + ln) * 20 + rg];             \
        }

    float* p1 = P1 + ((size_t)b * KB + kb) * 1024;
    float* p2 = P2 + ((size_t)b * KB + kb) * 1024;
    DUMP_REDUCE_G(D1, p1)
    DUMP_REDUCE_G(D2, p2)

    // ---- Q partial ----
    __syncthreads();
    #pragma unroll
    for (int i = 0; i < 4; ++i)
        *(float4*)&dmp[tid * 20 + 4 * i] = make_float4(DQ[4*i], DQ[4*i+1], DQ[4*i+2], DQ[4*i+3]);
    __syncthreads();
    if (tid < 96) {
        const int c2 = tid / 3, r2 = tid - 3 * c2;
        const int ln = r2 + 32 * ((c2 >> 2) & 1);
        const int rg = (c2 & 3) + 4 * (c2 >> 3);
        float s = dmp[ln * 20 + rg] + dmp[(64 + ln) * 20 + rg]
                + dmp[(128 + ln) * 20 + rg] + dmp[(192 + ln) * 20 + rg];
        Qp[((size_t)b * KB + kb) * 96 + tid] = s;
    }
}

// ---------------- k2: reduce partials -> S, Q; V = S*Q0; CholQR2 -> U (32x3, padded to 32x4) ----
__global__ __launch_bounds__(256)
void k2_solve(const float* __restrict__ P1, const float* __restrict__ P2,
              const float* __restrict__ Qp, float* __restrict__ Uo)
{
    const int b = blockIdx.x, tid = threadIdx.x;
    __shared__ float S[1024], A2[1024];
    __shared__ float Qv[96], V[96], G[6], L[6];

    // thread owns elements e = 4*tid .. 4*tid+3 (float4 loads, unrolled for MLP)
    f32x4 a1 = {0.f, 0.f, 0.f, 0.f}, a2 = {0.f, 0.f, 0.f, 0.f};
    const float4* p1 = (const float4*)(P1 + (size_t)b * KB * 1024);
    const float4* p2 = (const float4*)(P2 + (size_t)b * KB * 1024);
    #pragma unroll 4
    for (int kb = 0; kb < KB; ++kb) {
        float4 v1 = p1[kb * 256 + tid];
        float4 v2 = p2[kb * 256 + tid];
        a1.x += v1.x; a1.y += v1.y; a1.z += v1.z; a1.w += v1.w;
        a2.x += v2.x; a2.y += v2.y; a2.z += v2.z; a2.w += v2.w;
    }
    A2[4 * tid + 0] = a2.x; A2[4 * tid + 1] = a2.y;
    A2[4 * tid + 2] = a2.z; A2[4 * tid + 3] = a2.w;
    if (tid < 96) {
        const float* qp = Qp + (size_t)b * KB * 96;
        float q = 0.f;
        #pragma unroll 4
        for (int kb = 0; kb < KB; ++kb) q += qp[kb * 96 + tid];
        Qv[tid] = q;
    }
    __syncthreads();
    #pragma unroll
    for (int i = 0; i < 4; ++i) {
        const int e = 4 * tid + i;
        const int et = ((e & 31) << 5) | (e >> 5);
        S[e] = ((i == 0) ? a1.x : (i == 1) ? a1.y : (i == 2) ? a1.z : a1.w)
             + ((i == 0) ? a2.x : (i == 1) ? a2.y : (i == 2) ? a2.z : a2.w)
             + A2[et];
    }
    __syncthreads();

    if (tid < 96) {
        const int c = tid / 3, r = tid % 3;
        float s = 0.f;
        #pragma unroll 8
        for (int cc = 0; cc < 32; ++cc) s += S[c * 32 + cc] * Qv[cc * 3 + r];
        V[tid] = s;
    }
    for (int round = 0; round < 2; ++round) {
        __syncthreads();
        if (tid < 6) {
            const int r = (tid > 2) ? 2 : ((tid > 0) ? 1 : 0);
            const int s = tid - (r * (r + 1)) / 2;
            float g = 0.f;
            for (int c = 0; c < 32; ++c) g += V[c * 3 + r] * V[c * 3 + s];
            G[tid] = g;
        }
        __syncthreads();
        if (tid == 0) {
            const float l00 = sqrtf(G[0]);
            const float l10 = G[1] / l00, l20 = G[3] / l00;
            const float l11 = sqrtf(G[2] - l10 * l10);
            const float l21 = (G[4] - l20 * l10) / l11;
            const float l22 = sqrtf(G[5] - l20 * l20 - l21 * l21);
            L[0] = l00; L[1] = l10; L[2] = l11; L[3] = l20; L[4] = l21; L[5] = l22;
        }
        __syncthreads();
        if (tid < 32) {
            const float v0 = V[tid * 3 + 0], v1 = V[tid * 3 + 1], v2 = V[tid * 3 + 2];
            const float u0 = v0 / L[0];
            const float u1 = (v1 - L[1] * u0) / L[2];
            const float u2 = (v2 - L[3] * u0 - L[4] * u1) / L[5];
            V[tid * 3 + 0] = u0; V[tid * 3 + 1] = u1; V[tid * 3 + 2] = u2;
        }
    }
    __syncthreads();
    if (tid < 32) {
        Uo[(size_t)b * 128 + tid * 4 + 0] = V[tid * 3 + 0];
        Uo[(size_t)b * 128 + tid * 4 + 1] = V[tid * 3 + 1];
        Uo[(size_t)b * 128 + tid * 4 + 2] = V[tid * 3 + 2];
        Uo[(size_t)b * 128 + tid * 4 + 3] = 0.f;
    }
}

// ---------------- k3: out = U * (U^T X), pure streaming ----------------
__global__ __launch_bounds__(256)
void k3_out(const float* __restrict__ x, const float* __restrict__ Uw,
            float* __restrict__ out)
{
    const int b = blockIdx.y, tid = threadIdx.x;
    __shared__ float Us[32][4];
    if (tid < 128) ((float*)Us)[tid] = Uw[(size_t)b * 128 + tid];
    __syncthreads();
    const int g = blockIdx.x * 256 + tid;
    if (g >= N_HW / 4) return;

    const float* Xb = x   + (size_t)b * 32 * N_HW + 4 * (size_t)g;
    float*       Ob = out + (size_t)b * 32 * N_HW + 4 * (size_t)g;

    float t0x = 0, t0y = 0, t0z = 0, t0w = 0;
    float t1x = 0, t1y = 0, t1z = 0, t1w = 0;
    float t2x = 0, t2y = 0, t2z = 0, t2w = 0;
    #pragma unroll 16
    for (int c = 0; c < 32; ++c) {
        float4 xv = *(const float4*)(Xb + (size_t)c * N_HW);
        const float u0 = Us[c][0], u1 = Us[c][1], u2 = Us[c][2];
        t0x += u0 * xv.x; t0y += u0 * xv.y; t0z += u0 * xv.z; t0w += u0 * xv.w;
        t1x += u1 * xv.x; t1y += u1 * xv.y; t1z += u1 * xv.z; t1w += u1 * xv.w;
        t2x += u2 * xv.x; t2y += u2 * xv.y; t2z += u2 * xv.z; t2w += u2 * xv.w;
    }
    #pragma unroll 16
    for (int c = 0; c < 32; ++c) {
        const float u0 = Us[c][0], u1 = Us[c][1], u2 = Us[c][2];
        f32x4 o;
        o.x = u0 * t0x + u1 * t1x + u2 * t2x;
        o.y = u0 * t0y + u1 * t1y + u2 * t2y;
        o.z = u0 * t0z + u1 * t1z + u2 * t2z;
        o.w = u0 * t0w + u1 * t1w + u2 * t2w;
        __builtin_nontemporal_store(o, (f32x4*)(Ob + (size_t)c * N_HW));
    }
}

extern "C" void kernel_launch(void* const* d_in, const int* in_sizes, int n_in,
                              void* d_out, int out_size, void* d_ws, size_t ws_size,
                              hipStream_t stream)
{
    const float* x = (const float*)d_in[0];
    const float* p = (const float*)d_in[1];
    float* ws = (float*)d_ws;
    float* P1 = ws + WS_P1;
    float* P2 = ws + WS_P2;
    float* Qp = ws + WS_QP;
    float* U  = ws + WS_U;
    float* out = (float*)d_out;

    hipLaunchKernelGGL(k1_gram, dim3(KB, 64), dim3(256), 0, stream, x, p, P1, P2, Qp);
    hipLaunchKernelGGL(k2_solve, dim3(64), dim3(256), 0, stream, P1, P2, Qp, U);
    hipLaunchKernelGGL(k3_out, dim3((N_HW / 4 + 255) / 256, 64), dim3(256), 0, stream, x, U, out);
}